// Round 9
// baseline (432.910 us; speedup 1.0000x reference)
//
#include <hip/hip_runtime.h>
#include <hip/hip_bf16.h>
#include <math.h>

// ---------------------------------------------------------------------------
// GATv2 x2 on MI355X.  N=50000, E=400000, F_in=256, H=4, D=128, F_out=64
// Round 16: attn1 is traffic-bound: across r12-r15 dur == bytes/achieved_BW
// exactly (295MB / 3.5-3.8 TB/s). Lever = bytes & L2 hit rate, not VALU.
// Head-split attn1: wave = (node, head), 64 lanes x 2ch, gather granule
// 256B; head = blockIdx&3 so each head's 12.8MB x_l slice gets 2-XCD L2
// affinity under round-robin dispatch. Reduce = DPP row16 (proven correct
// by r10==r11) + shfl 16/32; w,l wave-uniform. Edge-loop guards verbatim
// from the 324.7us r12 anchor. GEMM / scans / casts / attn2 byte-identical.
// ---------------------------------------------------------------------------

#define NEG_SLOPE 0.2f
#define LOG2E 1.4426950408889634f

typedef _Float16 half8 __attribute__((ext_vector_type(8)));
typedef _Float16 h2 __attribute__((ext_vector_type(2)));
typedef float f32x4 __attribute__((ext_vector_type(4)));
typedef float f32x2 __attribute__((ext_vector_type(2)));

#if __has_builtin(__builtin_amdgcn_global_load_lds)
#define HAS_GLL 1
__device__ __forceinline__ void gll16(const _Float16* g, _Float16* l) {
    __builtin_amdgcn_global_load_lds(
        (const __attribute__((address_space(1))) unsigned int*)g,
        (__attribute__((address_space(3))) unsigned int*)l, 16, 0, 0);
}
#endif

__device__ __forceinline__ float dot2acc(h2 a, h2 b, float c) {
#if __has_builtin(__builtin_amdgcn_fdot2)
    return __builtin_amdgcn_fdot2(a, b, c, false);
#else
    return fmaf((float)a[1], (float)b[1], fmaf((float)a[0], (float)b[0], c));
#endif
}

__device__ __forceinline__ float fast_exp2(float p) {
#if __has_builtin(__builtin_amdgcn_exp2f)
    return __builtin_amdgcn_exp2f(p);
#else
    return exp2f(p);
#endif
}

// ---- DPP 16-lane sum-broadcast: proven semantically correct (r10 == r11) --

template <int CTRL>
__device__ __forceinline__ float dpp_addf(float x) {
    int y = __builtin_amdgcn_update_dpp(0, __builtin_bit_cast(int, x), CTRL, 0xF, 0xF, true);
    return x + __builtin_bit_cast(float, y);
}

__device__ __forceinline__ float row16_sum(float x) {
    x = dpp_addf<0xB1>(x);   // quad_perm xor1
    x = dpp_addf<0x4E>(x);   // quad_perm xor2
    x = dpp_addf<0x124>(x);  // row_ror:4
    x = dpp_addf<0x128>(x);  // row_ror:8
    return x;
}

// ---------------- fused cast_x + edge count (independent work) -------------

__global__ __launch_bounds__(256) void k_castx_count(const float* __restrict__ x, _Float16* __restrict__ xh,
                                                     int n8, const int* __restrict__ ei,
                                                     int* __restrict__ counts, int E, int Etot, int gEtot) {
    int b = blockIdx.x;
    if (b < gEtot) {
        int i = b * 256 + threadIdx.x;
        if (i < Etot) {
            int dst = (i < E) ? ei[E + i] : (i - E);
            atomicAdd(&counts[dst], 1);
        }
    } else {
        int i = (b - gEtot) * 256 + threadIdx.x;
        if (i < n8) {
            const float4* p = (const float4*)(x + i * 8);
            float4 a = p[0], c = p[1];
            half8 v;
            v[0] = (_Float16)a.x; v[1] = (_Float16)a.y; v[2] = (_Float16)a.z; v[3] = (_Float16)a.w;
            v[4] = (_Float16)c.x; v[5] = (_Float16)c.y; v[6] = (_Float16)c.z; v[7] = (_Float16)c.w;
            *(half8*)(xh + i * 8) = v;
        }
    }
}

// ---------------- fused cast_w + scan_a (independent work) -----------------

__global__ __launch_bounds__(1024) void k_castw_scana(const int* __restrict__ counts, int* __restrict__ offs,
                                                      int* __restrict__ partial, int n, int nsb,
                                                      const float* __restrict__ Wl1, const float* __restrict__ Wr1,
                                                      const float* __restrict__ Wl2, const float* __restrict__ Wr2,
                                                      _Float16* __restrict__ W1T, _Float16* __restrict__ W2T) {
    __shared__ int buf[1024];
    int b = blockIdx.x, t = threadIdx.x;
    if (b < nsb) {
        int i = b * 1024 + t;
        int v = (i < n) ? counts[i] : 0;
        buf[t] = v;
        __syncthreads();
        #pragma unroll
        for (int off = 1; off < 1024; off <<= 1) {
            int add = (t >= off) ? buf[t - off] : 0;
            __syncthreads();
            buf[t] += add;
            __syncthreads();
        }
        if (i < n) offs[i + 1] = buf[t];
        if (t == 1023) partial[b] = buf[1023];
    } else {
        int i = (b - nsb) * 1024 + t;
        const int T1 = 1024 * 256;
        const int T2 = 128 * 512;
        if (i < T1) {
            int nn = i >> 8, k = i & 255;
            float v = (nn < 512) ? Wl1[k * 512 + nn] : Wr1[k * 512 + (nn - 512)];
            W1T[i] = (_Float16)v;
        } else if (i < T1 + T2) {
            int j = i - T1;
            int nn = j >> 9, k = j & 511;
            float v = (nn < 64) ? Wl2[k * 64 + nn] : Wr2[k * 64 + (nn - 64)];
            W2T[j] = (_Float16)v;
        }
    }
}

// ---------------- merged scan_b + scan_c -----------------------------------

__global__ __launch_bounds__(256) void k_scanbc(int* __restrict__ offs, int* __restrict__ cursor,
                                                const int* __restrict__ partial, int n, int nsb) {
    __shared__ int s[256];
    int t = threadIdx.x;
    int v = (t < nsb) ? partial[t] : 0;
    s[t] = v;
    __syncthreads();
    #pragma unroll
    for (int off = 1; off < 256; off <<= 1) {
        int add = (t >= off) ? s[t - off] : 0;
        __syncthreads();
        s[t] += add;
        __syncthreads();
    }
    int excl = s[t] - v;
    s[t] = excl;
    __syncthreads();
    int i = blockIdx.x * 256 + t;
    if (i == 0) { offs[0] = 0; cursor[0] = 0; }
    if (i < n) {
        int w = offs[i + 1] + s[i >> 10];
        offs[i + 1] = w;
        cursor[i + 1] = w;
    }
}

// ------------------------------- GEMM f16 ----------------------------------
// C[M,N](f16) = A[M,K](f16) @ Bt[N,K](f16)^T. 128x128 tile, BK=32, 512 thr,
// 8 waves in 2(M)x4(N): each wave 64x32 -> 4x2 frags (32 AGPR). Staging:
// one global_load_lds per wave per operand (16 rows each). XOR chunk swizzle.

__device__ __forceinline__ void gemm_body(const _Float16* __restrict__ A,
                                          const _Float16* __restrict__ Bt,
                                          _Float16* __restrict__ C,
                                          int M, int N, int K, int ntiles, int blk,
                                          _Float16* As, _Float16* Bs) {
    int tid = threadIdx.x;
    int lane = tid & 63;
    int wave = tid >> 6;                  // 0..7
    int wm = wave >> 2, wn = wave & 3;    // 2 x 4 wave grid
    int l15 = lane & 15, q = lane >> 4;

    int ntile = blk % ntiles;
    int mtile = blk / ntiles;
    int tileM = mtile * 128;
    int tileN = ntile * 128;

    // staging: wave w stages rows [w*16, w*16+16) of A and of B (1 KB each)
    int srow = lane >> 2;                          // 0..15
    int schunk = (lane & 3) ^ ((lane >> 3) & 3);   // swizzled 16B chunk
    const _Float16* gA = A + (long)(tileM + wave * 16 + srow) * K + schunk * 8;
    const _Float16* gB = Bt + (long)(tileN + wave * 16 + srow) * K + schunk * 8;
    _Float16* lA = As + wave * 512;
    _Float16* lB = Bs + wave * 512;

    int aswz = (q ^ ((l15 >> 1) & 3)) * 8;         // reader chunk (halves)

    f32x4 acc[4][2];
    #pragma unroll
    for (int i = 0; i < 4; ++i)
        #pragma unroll
        for (int j = 0; j < 2; ++j)
            acc[i][j] = (f32x4)(0.f);

    for (int k0 = 0; k0 < K; k0 += 32) {
#ifdef HAS_GLL
        gll16(gA + k0, lA);
        gll16(gB + k0, lB);
#else
        half8 va = *(const half8*)(gA + k0);
        half8 vb = *(const half8*)(gB + k0);
        *(half8*)(lA + lane * 8) = va;
        *(half8*)(lB + lane * 8) = vb;
#endif
        __syncthreads();

        half8 af[4], bf[2];
        #pragma unroll
        for (int i = 0; i < 4; ++i)
            af[i] = *(const half8*)(As + (wm * 64 + i * 16 + l15) * 32 + aswz);
        #pragma unroll
        for (int j = 0; j < 2; ++j)
            bf[j] = *(const half8*)(Bs + (wn * 32 + j * 16 + l15) * 32 + aswz);
        #pragma unroll
        for (int i = 0; i < 4; ++i)
            #pragma unroll
            for (int j = 0; j < 2; ++j)
                acc[i][j] = __builtin_amdgcn_mfma_f32_16x16x32_f16(af[i], bf[j], acc[i][j], 0, 0, 0);
        __syncthreads();
    }

    #pragma unroll
    for (int i = 0; i < 4; ++i) {
        #pragma unroll
        for (int r = 0; r < 4; ++r) {
            int grow = tileM + wm * 64 + i * 16 + q * 4 + r;
            if (grow < M) {
                #pragma unroll
                for (int j = 0; j < 2; ++j) {
                    int gcol = tileN + wn * 32 + j * 16 + l15;
                    C[(long)grow * N + gcol] = (_Float16)acc[i][j][r];
                }
            }
        }
    }
}

// GEMM1 + CSR fill fused: first gb blocks do GEMM, rest do fill.
__global__ __launch_bounds__(512) void k_gemm1_fill(const _Float16* __restrict__ A,
                                                    const _Float16* __restrict__ Bt,
                                                    _Float16* __restrict__ C,
                                                    int M, int N, int K, int ntiles, int gb,
                                                    const int* __restrict__ ei, int* __restrict__ cursor,
                                                    int* __restrict__ csr_src, int E, int Etot) {
    __shared__ _Float16 As[128 * 32];
    __shared__ _Float16 Bs[128 * 32];
    int b = blockIdx.x;
    if (b < gb) {
        gemm_body(A, Bt, C, M, N, K, ntiles, b, As, Bs);
    } else {
        int i = (b - gb) * 512 + threadIdx.x;
        if (i < Etot) {
            int src, dst;
            if (i < E) { src = ei[i]; dst = ei[E + i]; }
            else       { src = i - E; dst = i - E; }
            int pos = atomicAdd(&cursor[dst], 1);
            csr_src[pos] = src;
        }
    }
}

__global__ __launch_bounds__(512) void k_gemm_f16(const _Float16* __restrict__ A,
                                                  const _Float16* __restrict__ Bt,
                                                  _Float16* __restrict__ C,
                                                  int M, int N, int K, int ntiles) {
    __shared__ _Float16 As[128 * 32];
    __shared__ _Float16 Bs[128 * 32];
    gemm_body(A, Bt, C, M, N, K, ntiles, blockIdx.x, As, Bs);
}

// --------------------- fused edge attention, layer 1 -----------------------
// HEAD-SPLIT: wave = (node, head). head = blockIdx&3 (2-XCD affinity per
// head under round-robin dispatch), node = (blockIdx>>2)*4 + wave.
// 64 lanes x 2 ch cover the head's 128 ch; gather = 256B/edge (lane dword).
// Reduce = DPP row16_sum + shfl_xor 16 + shfl_xor 32 (w, l wave-uniform).
// Edge-loop depth-2 prefetch and guards verbatim from the r12 anchor.

__global__ __launch_bounds__(256) void k_attn1(const _Float16* __restrict__ xlr,
                                               const float* __restrict__ att, const float* __restrict__ b1,
                                               const int* __restrict__ offs, const int* __restrict__ csr_src,
                                               _Float16* __restrict__ hout, int N) {
    int wave = threadIdx.x >> 6;
    int lane = threadIdx.x & 63;
    int head = blockIdx.x & 3;
    int node = (blockIdx.x >> 2) * 4 + wave;
    if (node >= N) return;

    int col = head * 128 + lane * 2;               // channel pair owned by lane
    const _Float16* xlr_l = xlr + col;             // per-lane base

    h2 xrh = *(const h2*)(xlr_l + ((unsigned)node << 10) + 512);
    float2 atf = *(const float2*)(att + col);
    h2 ath; ath[0] = (_Float16)(atf.x * LOG2E); ath[1] = (_Float16)(atf.y * LOG2E);
    const h2 ns2 = {(_Float16)NEG_SLOPE, (_Float16)NEG_SLOPE};

    float l = 0.f;
    float acc0 = 0.f, acc1 = 0.f;

    int e0 = offs[node], e1 = offs[node + 1];   // e1 > e0 (self-loop)
    int s_next = csr_src[e0];
    int s_next2 = (e0 + 1 < e1) ? csr_src[e0 + 1] : 0;
    h2 xlv = *(const h2*)(xlr_l + ((unsigned)s_next << 10));

    for (int e = e0; e < e1; ++e) {
        h2 cur = xlv;
        int s_pf = s_next2;
        if (e + 2 < e1) s_next2 = csr_src[e + 2];
        if (e + 1 < e1) xlv = *(const h2*)(xlr_l + ((unsigned)s_pf << 10));

        h2 t = cur + xrh;
#if __has_builtin(__builtin_elementwise_max)
        t = __builtin_elementwise_max(t, t * ns2);
#else
        h2 tn = t * ns2;
        t[0] = (t[0] > tn[0]) ? t[0] : tn[0];
        t[1] = (t[1] > tn[1]) ? t[1] : tn[1];
#endif
        float p = dot2acc(t, ath, 0.f);
        p = row16_sum(p);              // 16-lane sum (DPP, proven r10==r11)
        p += __shfl_xor(p, 16, 64);    // 32-lane sum
        p += __shfl_xor(p, 32, 64);    // full 64-lane sum -> head logit
        float w = fast_exp2(p);        // att pre-scaled by log2e
        l += w;
        acc0 = fmaf((float)cur[0], w, acc0);
        acc1 = fmaf((float)cur[1], w, acc1);
    }

    float inv = 1.f / (l + 1e-16f);
    float2 bf = *(const float2*)(b1 + col);
    float o0 = fmaf(acc0, inv, bf.x);
    float o1 = fmaf(acc1, inv, bf.y);
    o0 = (o0 > 0.f) ? o0 : (__expf(o0) - 1.f);
    o1 = (o1 > 0.f) ? o1 : (__expf(o1) - 1.f);
    h2 ov; ov[0] = (_Float16)o0; ov[1] = (_Float16)o1;
    *(h2*)(hout + (long)node * 512 + col) = ov;
}

// --------------------- fused edge attention, layer 2 -----------------------
// One wave per node, two edges/iter (half-wave each), 2 ch/lane (D=64).

__global__ __launch_bounds__(256) void k_attn2(const _Float16* __restrict__ xlr2,
                                               const float* __restrict__ att, const float* __restrict__ b2,
                                               const int* __restrict__ offs, const int* __restrict__ csr_src,
                                               float* __restrict__ out, int N) {
    int wave = threadIdx.x >> 6;
    int lane = threadIdx.x & 63;
    int node = blockIdx.x * 4 + wave;
    if (node >= N) return;

    int eh = lane >> 5;
    int hl = lane & 31;
    int ch = hl * 2;
    const _Float16* xlr_l = xlr2 + ch;

    h2 xrh = *(const h2*)(xlr_l + ((unsigned)node << 7) + 64);
    float2 atf = *(const float2*)(att + ch);
    h2 ath; ath[0] = (_Float16)(atf.x * LOG2E); ath[1] = (_Float16)(atf.y * LOG2E);
    const h2 ns2 = {(_Float16)NEG_SLOPE, (_Float16)NEG_SLOPE};

    float l = 0.f;
    f32x2 acc = (f32x2)(0.f);
    int e0 = offs[node], e1 = offs[node + 1];
    int e = e0 + eh;
    h2 cv;
    if (e < e1) {
        int s = csr_src[e];
        cv = *(const h2*)(xlr_l + ((unsigned)s << 7));
    }
    while (e < e1) {
        h2 u = cv;
        int en = e + 2;
        if (en < e1) {
            int s = csr_src[en];
            cv = *(const h2*)(xlr_l + ((unsigned)s << 7));
        }
        h2 t = u + xrh;
#if __has_builtin(__builtin_elementwise_max)
        t = __builtin_elementwise_max(t, t * ns2);
#else
        h2 tn = t * ns2;
        t[0] = (t[0] > tn[0]) ? t[0] : tn[0];
        t[1] = (t[1] > tn[1]) ? t[1] : tn[1];
#endif
        float p = dot2acc(t, ath, 0.f);
        p += __shfl_xor(p, 1, 64);
        p += __shfl_xor(p, 2, 64);
        p += __shfl_xor(p, 4, 64);
        p += __shfl_xor(p, 8, 64);
        p += __shfl_xor(p, 16, 64);
        float w = fast_exp2(p);
        l += w;
        f32x2 w2 = {w, w};
        f32x2 xf = {(float)u[0], (float)u[1]};
        acc = w2 * xf + acc;
        e = en;
    }
    l += __shfl_xor(l, 32, 64);
    acc[0] += __shfl_xor(acc[0], 32, 64);
    acc[1] += __shfl_xor(acc[1], 32, 64);
    if (eh == 0) {
        float inv = 1.f / (l + 1e-16f);
        float2 o;
        o.x = fmaf(acc[0], inv, b2[ch]);
        o.y = fmaf(acc[1], inv, b2[ch + 1]);
        *(float2*)(out + (long)node * 64 + ch) = o;
    }
}

// ---------------------------------------------------------------------------

extern "C" void kernel_launch(void* const* d_in, const int* in_sizes, int n_in,
                              void* d_out, int out_size, void* d_ws, size_t ws_size,
                              hipStream_t stream) {
    const float* x    = (const float*)d_in[0];
    const int*   ei   = (const int*)d_in[1];
    const float* Wl1  = (const float*)d_in[2];
    const float* Wr1  = (const float*)d_in[3];
    const float* att1 = (const float*)d_in[4];
    const float* b1   = (const float*)d_in[5];
    const float* Wl2  = (const float*)d_in[6];
    const float* Wr2  = (const float*)d_in[7];
    const float* att2 = (const float*)d_in[8];
    const float* b2   = (const float*)d_in[9];
    float* out = (float*)d_out;

    const int F_IN = 256;
    int N = in_sizes[0] / F_IN;   // 50000
    int E = in_sizes[1] / 2;      // 400000
    int Etot = E + N;
    int nScanBlocks = (N + 1023) / 1024;
    int mtiles = (N + 127) / 128;
    int Mpad = mtiles * 128;      // A buffers padded so GEMM can load OOB rows

    char* p = (char*)d_ws;
    auto carve = [&](size_t bytes) -> void* {
        void* r = (void*)p;
        p += (bytes + 255) & ~(size_t)255;
        return r;
    };
    _Float16* xh   = (_Float16*)carve((size_t)Mpad * 256 * 2);
    _Float16* W1T  = (_Float16*)carve((size_t)1024 * 256 * 2);
    _Float16* W2T  = (_Float16*)carve((size_t)128 * 512 * 2);
    _Float16* C1   = (_Float16*)carve((size_t)N * 1024 * 2);
    _Float16* h    = (_Float16*)carve((size_t)Mpad * 512 * 2);
    _Float16* C2   = (_Float16*)carve((size_t)N * 128 * 2);
    int* counts  = (int*)carve((size_t)N * 4);
    int* offs    = (int*)carve((size_t)(N + 1) * 4);
    int* cursor  = (int*)carve((size_t)(N + 1) * 4);
    int* partial = (int*)carve((size_t)nScanBlocks * 4);
    int* csr     = (int*)carve((size_t)Etot * 4);

    int gN    = (N + 255) / 256;
    int gEtot = (Etot + 255) / 256;
    int n8    = N * 256 / 8;
    int gCast = (n8 + 255) / 256;

    hipMemsetAsync(counts, 0, (size_t)N * 4, stream);

    // cast_x || count  (independent)
    k_castx_count<<<gEtot + gCast, 256, 0, stream>>>(x, xh, n8, ei, counts, E, Etot, gEtot);

    // cast_w || scan_a  (independent)
    {
        int total = 1024 * 256 + 128 * 512;
        int gW = (total + 1023) / 1024;
        k_castw_scana<<<nScanBlocks + gW, 1024, 0, stream>>>(counts, offs, partial, N, nScanBlocks,
                                                             Wl1, Wr1, Wl2, Wr2, W1T, W2T);
    }
    // merged scan_b + scan_c
    k_scanbc<<<gN, 256, 0, stream>>>(offs, cursor, partial, N, nScanBlocks);

    // layer 1 GEMM (N-tile inner for A reuse) || CSR fill (independent)
    {
        int gb = mtiles * 8;
        int fillBlocks = (Etot + 511) / 512;
        k_gemm1_fill<<<gb + fillBlocks, 512, 0, stream>>>(xh, W1T, C1, N, 1024, 256, 8, gb,
                                                          ei, cursor, csr, E, Etot);
    }
    // head-split attn1: blocks = node_groups * 4 heads
    {
        int nb = ((N + 3) / 4) * 4;
        k_attn1<<<nb, 256, 0, stream>>>(C1, att1, b1, offs, csr, h, N);
    }

    // layer 2
    k_gemm_f16<<<mtiles, 512, 0, stream>>>(h, W2T, C2, N, 128, 512, 1);
    k_attn2<<<(N + 3) / 4, 256, 0, stream>>>(C2, att2, b2, offs, csr, out, N);
}

// Round 10
// 328.456 us; speedup vs baseline: 1.3180x; 1.3180x over previous
//
#include <hip/hip_runtime.h>
#include <hip/hip_bf16.h>
#include <math.h>

// ---------------------------------------------------------------------------
// GATv2 x2 on MI355X.  N=50000, E=400000, F_in=256, H=4, D=128, F_out=64
// Round 17: r12 anchor (324.7us) + ONE change: attn kernels use 128-thread
// blocks (2 waves). r12's 65% occupancy == E[avg/max of 4 Poisson degree
// draws] (block slot held by slowest wave). 2-wave blocks: WG/CU cap x 2
// fills all 32 wave slots, imbalance factor 0.78 -> ~78% effective. Gather
// granule stays 1KB (r15/r16 proved BW collapses with smaller granules).
// Bodies byte-identical to r12. GEMM / scans / casts unchanged.
// Ladder: granule->BW: 1KB=3.79, 512B=3.51, 256B=1.39 TB/s. dur==FETCH/BW
// in r12..r16 (5/5). attn1 floor at current FETCH ~ 63us.
// ---------------------------------------------------------------------------

#define NEG_SLOPE 0.2f
#define LOG2E 1.4426950408889634f

typedef _Float16 half8 __attribute__((ext_vector_type(8)));
typedef _Float16 h2 __attribute__((ext_vector_type(2)));
typedef float f32x4 __attribute__((ext_vector_type(4)));
typedef float f32x2 __attribute__((ext_vector_type(2)));

#if __has_builtin(__builtin_amdgcn_global_load_lds)
#define HAS_GLL 1
__device__ __forceinline__ void gll16(const _Float16* g, _Float16* l) {
    __builtin_amdgcn_global_load_lds(
        (const __attribute__((address_space(1))) unsigned int*)g,
        (__attribute__((address_space(3))) unsigned int*)l, 16, 0, 0);
}
#endif

__device__ __forceinline__ float dot2acc(h2 a, h2 b, float c) {
#if __has_builtin(__builtin_amdgcn_fdot2)
    return __builtin_amdgcn_fdot2(a, b, c, false);
#else
    return fmaf((float)a[1], (float)b[1], fmaf((float)a[0], (float)b[0], c));
#endif
}

__device__ __forceinline__ float fast_exp2(float p) {
#if __has_builtin(__builtin_amdgcn_exp2f)
    return __builtin_amdgcn_exp2f(p);
#else
    return exp2f(p);
#endif
}

// ---------------- fused cast_x + edge count (independent work) -------------

__global__ __launch_bounds__(256) void k_castx_count(const float* __restrict__ x, _Float16* __restrict__ xh,
                                                     int n8, const int* __restrict__ ei,
                                                     int* __restrict__ counts, int E, int Etot, int gEtot) {
    int b = blockIdx.x;
    if (b < gEtot) {
        int i = b * 256 + threadIdx.x;
        if (i < Etot) {
            int dst = (i < E) ? ei[E + i] : (i - E);
            atomicAdd(&counts[dst], 1);
        }
    } else {
        int i = (b - gEtot) * 256 + threadIdx.x;
        if (i < n8) {
            const float4* p = (const float4*)(x + i * 8);
            float4 a = p[0], c = p[1];
            half8 v;
            v[0] = (_Float16)a.x; v[1] = (_Float16)a.y; v[2] = (_Float16)a.z; v[3] = (_Float16)a.w;
            v[4] = (_Float16)c.x; v[5] = (_Float16)c.y; v[6] = (_Float16)c.z; v[7] = (_Float16)c.w;
            *(half8*)(xh + i * 8) = v;
        }
    }
}

// ---------------- fused cast_w + scan_a (independent work) -----------------

__global__ __launch_bounds__(1024) void k_castw_scana(const int* __restrict__ counts, int* __restrict__ offs,
                                                      int* __restrict__ partial, int n, int nsb,
                                                      const float* __restrict__ Wl1, const float* __restrict__ Wr1,
                                                      const float* __restrict__ Wl2, const float* __restrict__ Wr2,
                                                      _Float16* __restrict__ W1T, _Float16* __restrict__ W2T) {
    __shared__ int buf[1024];
    int b = blockIdx.x, t = threadIdx.x;
    if (b < nsb) {
        int i = b * 1024 + t;
        int v = (i < n) ? counts[i] : 0;
        buf[t] = v;
        __syncthreads();
        #pragma unroll
        for (int off = 1; off < 1024; off <<= 1) {
            int add = (t >= off) ? buf[t - off] : 0;
            __syncthreads();
            buf[t] += add;
            __syncthreads();
        }
        if (i < n) offs[i + 1] = buf[t];
        if (t == 1023) partial[b] = buf[1023];
    } else {
        int i = (b - nsb) * 1024 + t;
        const int T1 = 1024 * 256;
        const int T2 = 128 * 512;
        if (i < T1) {
            int nn = i >> 8, k = i & 255;
            float v = (nn < 512) ? Wl1[k * 512 + nn] : Wr1[k * 512 + (nn - 512)];
            W1T[i] = (_Float16)v;
        } else if (i < T1 + T2) {
            int j = i - T1;
            int nn = j >> 9, k = j & 511;
            float v = (nn < 64) ? Wl2[k * 64 + nn] : Wr2[k * 64 + (nn - 64)];
            W2T[j] = (_Float16)v;
        }
    }
}

// ---------------- merged scan_b + scan_c -----------------------------------

__global__ __launch_bounds__(256) void k_scanbc(int* __restrict__ offs, int* __restrict__ cursor,
                                                const int* __restrict__ partial, int n, int nsb) {
    __shared__ int s[256];
    int t = threadIdx.x;
    int v = (t < nsb) ? partial[t] : 0;
    s[t] = v;
    __syncthreads();
    #pragma unroll
    for (int off = 1; off < 256; off <<= 1) {
        int add = (t >= off) ? s[t - off] : 0;
        __syncthreads();
        s[t] += add;
        __syncthreads();
    }
    int excl = s[t] - v;
    s[t] = excl;
    __syncthreads();
    int i = blockIdx.x * 256 + t;
    if (i == 0) { offs[0] = 0; cursor[0] = 0; }
    if (i < n) {
        int w = offs[i + 1] + s[i >> 10];
        offs[i + 1] = w;
        cursor[i + 1] = w;
    }
}

// ------------------------------- GEMM f16 ----------------------------------
// C[M,N](f16) = A[M,K](f16) @ Bt[N,K](f16)^T. 128x128 tile, BK=32, 512 thr,
// 8 waves in 2(M)x4(N): each wave 64x32 -> 4x2 frags (32 AGPR). Staging:
// one global_load_lds per wave per operand (16 rows each). XOR chunk swizzle.

__device__ __forceinline__ void gemm_body(const _Float16* __restrict__ A,
                                          const _Float16* __restrict__ Bt,
                                          _Float16* __restrict__ C,
                                          int M, int N, int K, int ntiles, int blk,
                                          _Float16* As, _Float16* Bs) {
    int tid = threadIdx.x;
    int lane = tid & 63;
    int wave = tid >> 6;                  // 0..7
    int wm = wave >> 2, wn = wave & 3;    // 2 x 4 wave grid
    int l15 = lane & 15, q = lane >> 4;

    int ntile = blk % ntiles;
    int mtile = blk / ntiles;
    int tileM = mtile * 128;
    int tileN = ntile * 128;

    // staging: wave w stages rows [w*16, w*16+16) of A and of B (1 KB each)
    int srow = lane >> 2;                          // 0..15
    int schunk = (lane & 3) ^ ((lane >> 3) & 3);   // swizzled 16B chunk
    const _Float16* gA = A + (long)(tileM + wave * 16 + srow) * K + schunk * 8;
    const _Float16* gB = Bt + (long)(tileN + wave * 16 + srow) * K + schunk * 8;
    _Float16* lA = As + wave * 512;
    _Float16* lB = Bs + wave * 512;

    int aswz = (q ^ ((l15 >> 1) & 3)) * 8;         // reader chunk (halves)

    f32x4 acc[4][2];
    #pragma unroll
    for (int i = 0; i < 4; ++i)
        #pragma unroll
        for (int j = 0; j < 2; ++j)
            acc[i][j] = (f32x4)(0.f);

    for (int k0 = 0; k0 < K; k0 += 32) {
#ifdef HAS_GLL
        gll16(gA + k0, lA);
        gll16(gB + k0, lB);
#else
        half8 va = *(const half8*)(gA + k0);
        half8 vb = *(const half8*)(gB + k0);
        *(half8*)(lA + lane * 8) = va;
        *(half8*)(lB + lane * 8) = vb;
#endif
        __syncthreads();

        half8 af[4], bf[2];
        #pragma unroll
        for (int i = 0; i < 4; ++i)
            af[i] = *(const half8*)(As + (wm * 64 + i * 16 + l15) * 32 + aswz);
        #pragma unroll
        for (int j = 0; j < 2; ++j)
            bf[j] = *(const half8*)(Bs + (wn * 32 + j * 16 + l15) * 32 + aswz);
        #pragma unroll
        for (int i = 0; i < 4; ++i)
            #pragma unroll
            for (int j = 0; j < 2; ++j)
                acc[i][j] = __builtin_amdgcn_mfma_f32_16x16x32_f16(af[i], bf[j], acc[i][j], 0, 0, 0);
        __syncthreads();
    }

    #pragma unroll
    for (int i = 0; i < 4; ++i) {
        #pragma unroll
        for (int r = 0; r < 4; ++r) {
            int grow = tileM + wm * 64 + i * 16 + q * 4 + r;
            if (grow < M) {
                #pragma unroll
                for (int j = 0; j < 2; ++j) {
                    int gcol = tileN + wn * 32 + j * 16 + l15;
                    C[(long)grow * N + gcol] = (_Float16)acc[i][j][r];
                }
            }
        }
    }
}

// GEMM1 + CSR fill fused: first gb blocks do GEMM, rest do fill.
__global__ __launch_bounds__(512) void k_gemm1_fill(const _Float16* __restrict__ A,
                                                    const _Float16* __restrict__ Bt,
                                                    _Float16* __restrict__ C,
                                                    int M, int N, int K, int ntiles, int gb,
                                                    const int* __restrict__ ei, int* __restrict__ cursor,
                                                    int* __restrict__ csr_src, int E, int Etot) {
    __shared__ _Float16 As[128 * 32];
    __shared__ _Float16 Bs[128 * 32];
    int b = blockIdx.x;
    if (b < gb) {
        gemm_body(A, Bt, C, M, N, K, ntiles, b, As, Bs);
    } else {
        int i = (b - gb) * 512 + threadIdx.x;
        if (i < Etot) {
            int src, dst;
            if (i < E) { src = ei[i]; dst = ei[E + i]; }
            else       { src = i - E; dst = i - E; }
            int pos = atomicAdd(&cursor[dst], 1);
            csr_src[pos] = src;
        }
    }
}

__global__ __launch_bounds__(512) void k_gemm_f16(const _Float16* __restrict__ A,
                                                  const _Float16* __restrict__ Bt,
                                                  _Float16* __restrict__ C,
                                                  int M, int N, int K, int ntiles) {
    __shared__ _Float16 As[128 * 32];
    __shared__ _Float16 Bs[128 * 32];
    gemm_body(A, Bt, C, M, N, K, ntiles, blockIdx.x, As, Bs);
}

// --------------------- fused edge attention, layer 1 -----------------------
// 2 waves per block (occupancy: WG-slot cap x 2 waves fills 32 slots; 2-draw
// degree imbalance 0.78 vs 4-draw 0.65). Body identical to r12: one wave per
// node, 4 heads (head = lane>>4, 8 ch/lane), 1 edge/iter, depth-2 prefetch.

__global__ __launch_bounds__(128) void k_attn1(const _Float16* __restrict__ xlr,
                                               const float* __restrict__ att, const float* __restrict__ b1,
                                               const int* __restrict__ offs, const int* __restrict__ csr_src,
                                               _Float16* __restrict__ hout, int N) {
    int wave = threadIdx.x >> 6;
    int lane = threadIdx.x & 63;
    int node = blockIdx.x * 2 + wave;
    if (node >= N) return;

    int cbase = (lane >> 4) * 128 + (lane & 15) * 8;
    const _Float16* xlr_l = xlr + cbase;           // per-lane base

    half8 xrv8 = *(const half8*)(xlr_l + ((unsigned)node << 10) + 512);
    float4 atv0 = *(const float4*)(att + cbase);
    float4 atv1 = *(const float4*)(att + cbase + 4);
    h2 xr[4], at[4];
    #pragma unroll
    for (int j = 0; j < 4; ++j) {
        xr[j][0] = xrv8[2 * j]; xr[j][1] = xrv8[2 * j + 1];
    }
    at[0][0] = (_Float16)(atv0.x * LOG2E); at[0][1] = (_Float16)(atv0.y * LOG2E);
    at[1][0] = (_Float16)(atv0.z * LOG2E); at[1][1] = (_Float16)(atv0.w * LOG2E);
    at[2][0] = (_Float16)(atv1.x * LOG2E); at[2][1] = (_Float16)(atv1.y * LOG2E);
    at[3][0] = (_Float16)(atv1.z * LOG2E); at[3][1] = (_Float16)(atv1.w * LOG2E);
    const h2 ns2 = {(_Float16)NEG_SLOPE, (_Float16)NEG_SLOPE};

    float l = 0.f;
    f32x2 acc[4];
    #pragma unroll
    for (int j = 0; j < 4; ++j) acc[j] = (f32x2)(0.f);

    int e0 = offs[node], e1 = offs[node + 1];   // e1 > e0 (self-loop)
    int s_next = csr_src[e0];
    int s_next2 = (e0 + 1 < e1) ? csr_src[e0 + 1] : 0;
    half8 xlv = *(const half8*)(xlr_l + ((unsigned)s_next << 10));

    for (int e = e0; e < e1; ++e) {
        half8 cur = xlv;
        int s_pf = s_next2;
        if (e + 2 < e1) s_next2 = csr_src[e + 2];
        if (e + 1 < e1) xlv = *(const half8*)(xlr_l + ((unsigned)s_pf << 10));

        const h2* cp = (const h2*)&cur;
        float p = 0.f;
        #pragma unroll
        for (int j = 0; j < 4; ++j) {
            h2 t = cp[j] + xr[j];
#if __has_builtin(__builtin_elementwise_max)
            t = __builtin_elementwise_max(t, t * ns2);
#else
            h2 tn = t * ns2;
            t[0] = (t[0] > tn[0]) ? t[0] : tn[0];
            t[1] = (t[1] > tn[1]) ? t[1] : tn[1];
#endif
            p = dot2acc(t, at[j], p);
        }
        #pragma unroll
        for (int off = 1; off <= 8; off <<= 1) p += __shfl_xor(p, off, 64);
        float w = fast_exp2(p);        // == exp(logit): att pre-scaled by log2e
        l += w;
        f32x2 w2 = {w, w};
        #pragma unroll
        for (int j = 0; j < 4; ++j) {
            f32x2 xf = {(float)cur[2 * j], (float)cur[2 * j + 1]};
            acc[j] = w2 * xf + acc[j];
        }
    }

    float inv = 1.f / (l + 1e-16f);
    float4 b1v0 = *(const float4*)(b1 + cbase);
    float4 b1v1 = *(const float4*)(b1 + cbase + 4);
    float bb[8] = {b1v0.x, b1v0.y, b1v0.z, b1v0.w, b1v1.x, b1v1.y, b1v1.z, b1v1.w};
    half8 ov;
    #pragma unroll
    for (int j = 0; j < 8; ++j) {
        float o = fmaf(acc[j >> 1][j & 1], inv, bb[j]);
        o = (o > 0.f) ? o : (__expf(o) - 1.f);
        ov[j] = (_Float16)o;
    }
    *(half8*)(hout + (long)node * 512 + cbase) = ov;
}

// --------------------- fused edge attention, layer 2 -----------------------
// 2 waves per block; per node two edges/iter (half-wave each), 2 ch/lane.

__global__ __launch_bounds__(128) void k_attn2(const _Float16* __restrict__ xlr2,
                                               const float* __restrict__ att, const float* __restrict__ b2,
                                               const int* __restrict__ offs, const int* __restrict__ csr_src,
                                               float* __restrict__ out, int N) {
    int wave = threadIdx.x >> 6;
    int lane = threadIdx.x & 63;
    int node = blockIdx.x * 2 + wave;
    if (node >= N) return;

    int eh = lane >> 5;
    int hl = lane & 31;
    int ch = hl * 2;
    const _Float16* xlr_l = xlr2 + ch;

    h2 xrh = *(const h2*)(xlr_l + ((unsigned)node << 7) + 64);
    float2 atf = *(const float2*)(att + ch);
    h2 ath; ath[0] = (_Float16)(atf.x * LOG2E); ath[1] = (_Float16)(atf.y * LOG2E);
    const h2 ns2 = {(_Float16)NEG_SLOPE, (_Float16)NEG_SLOPE};

    float l = 0.f;
    f32x2 acc = (f32x2)(0.f);
    int e0 = offs[node], e1 = offs[node + 1];
    int e = e0 + eh;
    h2 cv;
    if (e < e1) {
        int s = csr_src[e];
        cv = *(const h2*)(xlr_l + ((unsigned)s << 7));
    }
    while (e < e1) {
        h2 u = cv;
        int en = e + 2;
        if (en < e1) {
            int s = csr_src[en];
            cv = *(const h2*)(xlr_l + ((unsigned)s << 7));
        }
        h2 t = u + xrh;
#if __has_builtin(__builtin_elementwise_max)
        t = __builtin_elementwise_max(t, t * ns2);
#else
        h2 tn = t * ns2;
        t[0] = (t[0] > tn[0]) ? t[0] : tn[0];
        t[1] = (t[1] > tn[1]) ? t[1] : tn[1];
#endif
        float p = dot2acc(t, ath, 0.f);
        p += __shfl_xor(p, 1, 64);
        p += __shfl_xor(p, 2, 64);
        p += __shfl_xor(p, 4, 64);
        p += __shfl_xor(p, 8, 64);
        p += __shfl_xor(p, 16, 64);
        float w = fast_exp2(p);
        l += w;
        f32x2 w2 = {w, w};
        f32x2 xf = {(float)u[0], (float)u[1]};
        acc = w2 * xf + acc;
        e = en;
    }
    l += __shfl_xor(l, 32, 64);
    acc[0] += __shfl_xor(acc[0], 32, 64);
    acc[1] += __shfl_xor(acc[1], 32, 64);
    if (eh == 0) {
        float inv = 1.f / (l + 1e-16f);
        float2 o;
        o.x = fmaf(acc[0], inv, b2[ch]);
        o.y = fmaf(acc[1], inv, b2[ch + 1]);
        *(float2*)(out + (long)node * 64 + ch) = o;
    }
}

// ---------------------------------------------------------------------------

extern "C" void kernel_launch(void* const* d_in, const int* in_sizes, int n_in,
                              void* d_out, int out_size, void* d_ws, size_t ws_size,
                              hipStream_t stream) {
    const float* x    = (const float*)d_in[0];
    const int*   ei   = (const int*)d_in[1];
    const float* Wl1  = (const float*)d_in[2];
    const float* Wr1  = (const float*)d_in[3];
    const float* att1 = (const float*)d_in[4];
    const float* b1   = (const float*)d_in[5];
    const float* Wl2  = (const float*)d_in[6];
    const float* Wr2  = (const float*)d_in[7];
    const float* att2 = (const float*)d_in[8];
    const float* b2   = (const float*)d_in[9];
    float* out = (float*)d_out;

    const int F_IN = 256;
    int N = in_sizes[0] / F_IN;   // 50000
    int E = in_sizes[1] / 2;      // 400000
    int Etot = E + N;
    int nScanBlocks = (N + 1023) / 1024;
    int mtiles = (N + 127) / 128;
    int Mpad = mtiles * 128;      // A buffers padded so GEMM can load OOB rows

    char* p = (char*)d_ws;
    auto carve = [&](size_t bytes) -> void* {
        void* r = (void*)p;
        p += (bytes + 255) & ~(size_t)255;
        return r;
    };
    _Float16* xh   = (_Float16*)carve((size_t)Mpad * 256 * 2);
    _Float16* W1T  = (_Float16*)carve((size_t)1024 * 256 * 2);
    _Float16* W2T  = (_Float16*)carve((size_t)128 * 512 * 2);
    _Float16* C1   = (_Float16*)carve((size_t)N * 1024 * 2);
    _Float16* h    = (_Float16*)carve((size_t)Mpad * 512 * 2);
    _Float16* C2   = (_Float16*)carve((size_t)N * 128 * 2);
    int* counts  = (int*)carve((size_t)N * 4);
    int* offs    = (int*)carve((size_t)(N + 1) * 4);
    int* cursor  = (int*)carve((size_t)(N + 1) * 4);
    int* partial = (int*)carve((size_t)nScanBlocks * 4);
    int* csr     = (int*)carve((size_t)Etot * 4);

    int gN    = (N + 255) / 256;
    int gEtot = (Etot + 255) / 256;
    int n8    = N * 256 / 8;
    int gCast = (n8 + 255) / 256;

    hipMemsetAsync(counts, 0, (size_t)N * 4, stream);

    // cast_x || count  (independent)
    k_castx_count<<<gEtot + gCast, 256, 0, stream>>>(x, xh, n8, ei, counts, E, Etot, gEtot);

    // cast_w || scan_a  (independent)
    {
        int total = 1024 * 256 + 128 * 512;
        int gW = (total + 1023) / 1024;
        k_castw_scana<<<nScanBlocks + gW, 1024, 0, stream>>>(counts, offs, partial, N, nScanBlocks,
                                                             Wl1, Wr1, Wl2, Wr2, W1T, W2T);
    }
    // merged scan_b + scan_c
    k_scanbc<<<gN, 256, 0, stream>>>(offs, cursor, partial, N, nScanBlocks);

    // layer 1 GEMM (N-tile inner for A reuse) || CSR fill (independent)
    {
        int gb = mtiles * 8;
        int fillBlocks = (Etot + 511) / 512;
        k_gemm1_fill<<<gb + fillBlocks, 512, 0, stream>>>(xh, W1T, C1, N, 1024, 256, 8, gb,
                                                          ei, cursor, csr, E, Etot);
    }
    // 2-wave blocks for occupancy (wave-slot fill)
    k_attn1<<<(N + 1) / 2, 128, 0, stream>>>(C1, att1, b1, offs, csr, h, N);

    // layer 2
    k_gemm_f16<<<mtiles, 512, 0, stream>>>(h, W2T, C2, N, 128, 512, 1);
    k_attn2<<<(N + 1) / 2, 128, 0, stream>>>(C2, att2, b2, offs, csr, out, N);
}

// Round 11
// 322.063 us; speedup vs baseline: 1.3442x; 1.0199x over previous
//
#include <hip/hip_runtime.h>
#include <hip/hip_bf16.h>
#include <math.h>

// ---------------------------------------------------------------------------
// GATv2 x2 on MI355X.  N=50000, E=400000, F_in=256, H=4, D=128, F_out=64
// Round 18: r12 anchor (324.7us, proven) + ONE substitution: the per-edge
// 16-lane reduce uses DPP row16_sum (4 VALU adds, harness-proven in r16)
// instead of 4 dependent ds_permute shfl_xor (~130cy serial LDS-pipe wait
// per edge). attn2: first 4 reduce steps likewise, + shfl_xor(16) (the
// exact r16-proven combination). EVERYTHING else byte-identical to r12.
// Ledger: FETCH pinned 238MB, dur 78us across 7 structural experiments;
// granule ladder 1KB=3.79/512B=3.51/256B=1.39 TB/s. If this is flat too,
// attn1 is pattern-bound -> roofline.
// ---------------------------------------------------------------------------

#define NEG_SLOPE 0.2f
#define LOG2E 1.4426950408889634f

typedef _Float16 half8 __attribute__((ext_vector_type(8)));
typedef _Float16 h2 __attribute__((ext_vector_type(2)));
typedef float f32x4 __attribute__((ext_vector_type(4)));
typedef float f32x2 __attribute__((ext_vector_type(2)));

#if __has_builtin(__builtin_amdgcn_global_load_lds)
#define HAS_GLL 1
__device__ __forceinline__ void gll16(const _Float16* g, _Float16* l) {
    __builtin_amdgcn_global_load_lds(
        (const __attribute__((address_space(1))) unsigned int*)g,
        (__attribute__((address_space(3))) unsigned int*)l, 16, 0, 0);
}
#endif

__device__ __forceinline__ float dot2acc(h2 a, h2 b, float c) {
#if __has_builtin(__builtin_amdgcn_fdot2)
    return __builtin_amdgcn_fdot2(a, b, c, false);
#else
    return fmaf((float)a[1], (float)b[1], fmaf((float)a[0], (float)b[0], c));
#endif
}

__device__ __forceinline__ float fast_exp2(float p) {
#if __has_builtin(__builtin_amdgcn_exp2f)
    return __builtin_amdgcn_exp2f(p);
#else
    return exp2f(p);
#endif
}

// ---- DPP 16-lane sum-broadcast: harness-proven (r16 passed; r10==r11) ----

template <int CTRL>
__device__ __forceinline__ float dpp_addf(float x) {
    int y = __builtin_amdgcn_update_dpp(0, __builtin_bit_cast(int, x), CTRL, 0xF, 0xF, true);
    return x + __builtin_bit_cast(float, y);
}

__device__ __forceinline__ float row16_sum(float x) {
    x = dpp_addf<0xB1>(x);   // quad_perm xor1
    x = dpp_addf<0x4E>(x);   // quad_perm xor2
    x = dpp_addf<0x124>(x);  // row_ror:4
    x = dpp_addf<0x128>(x);  // row_ror:8
    return x;
}

// ---------------- fused cast_x + edge count (independent work) -------------

__global__ __launch_bounds__(256) void k_castx_count(const float* __restrict__ x, _Float16* __restrict__ xh,
                                                     int n8, const int* __restrict__ ei,
                                                     int* __restrict__ counts, int E, int Etot, int gEtot) {
    int b = blockIdx.x;
    if (b < gEtot) {
        int i = b * 256 + threadIdx.x;
        if (i < Etot) {
            int dst = (i < E) ? ei[E + i] : (i - E);
            atomicAdd(&counts[dst], 1);
        }
    } else {
        int i = (b - gEtot) * 256 + threadIdx.x;
        if (i < n8) {
            const float4* p = (const float4*)(x + i * 8);
            float4 a = p[0], c = p[1];
            half8 v;
            v[0] = (_Float16)a.x; v[1] = (_Float16)a.y; v[2] = (_Float16)a.z; v[3] = (_Float16)a.w;
            v[4] = (_Float16)c.x; v[5] = (_Float16)c.y; v[6] = (_Float16)c.z; v[7] = (_Float16)c.w;
            *(half8*)(xh + i * 8) = v;
        }
    }
}

// ---------------- fused cast_w + scan_a (independent work) -----------------

__global__ __launch_bounds__(1024) void k_castw_scana(const int* __restrict__ counts, int* __restrict__ offs,
                                                      int* __restrict__ partial, int n, int nsb,
                                                      const float* __restrict__ Wl1, const float* __restrict__ Wr1,
                                                      const float* __restrict__ Wl2, const float* __restrict__ Wr2,
                                                      _Float16* __restrict__ W1T, _Float16* __restrict__ W2T) {
    __shared__ int buf[1024];
    int b = blockIdx.x, t = threadIdx.x;
    if (b < nsb) {
        int i = b * 1024 + t;
        int v = (i < n) ? counts[i] : 0;
        buf[t] = v;
        __syncthreads();
        #pragma unroll
        for (int off = 1; off < 1024; off <<= 1) {
            int add = (t >= off) ? buf[t - off] : 0;
            __syncthreads();
            buf[t] += add;
            __syncthreads();
        }
        if (i < n) offs[i + 1] = buf[t];
        if (t == 1023) partial[b] = buf[1023];
    } else {
        int i = (b - nsb) * 1024 + t;
        const int T1 = 1024 * 256;
        const int T2 = 128 * 512;
        if (i < T1) {
            int nn = i >> 8, k = i & 255;
            float v = (nn < 512) ? Wl1[k * 512 + nn] : Wr1[k * 512 + (nn - 512)];
            W1T[i] = (_Float16)v;
        } else if (i < T1 + T2) {
            int j = i - T1;
            int nn = j >> 9, k = j & 511;
            float v = (nn < 64) ? Wl2[k * 64 + nn] : Wr2[k * 64 + (nn - 64)];
            W2T[j] = (_Float16)v;
        }
    }
}

// ---------------- merged scan_b + scan_c -----------------------------------

__global__ __launch_bounds__(256) void k_scanbc(int* __restrict__ offs, int* __restrict__ cursor,
                                                const int* __restrict__ partial, int n, int nsb) {
    __shared__ int s[256];
    int t = threadIdx.x;
    int v = (t < nsb) ? partial[t] : 0;
    s[t] = v;
    __syncthreads();
    #pragma unroll
    for (int off = 1; off < 256; off <<= 1) {
        int add = (t >= off) ? s[t - off] : 0;
        __syncthreads();
        s[t] += add;
        __syncthreads();
    }
    int excl = s[t] - v;
    s[t] = excl;
    __syncthreads();
    int i = blockIdx.x * 256 + t;
    if (i == 0) { offs[0] = 0; cursor[0] = 0; }
    if (i < n) {
        int w = offs[i + 1] + s[i >> 10];
        offs[i + 1] = w;
        cursor[i + 1] = w;
    }
}

// ------------------------------- GEMM f16 ----------------------------------
// C[M,N](f16) = A[M,K](f16) @ Bt[N,K](f16)^T. 128x128 tile, BK=32, 512 thr,
// 8 waves in 2(M)x4(N): each wave 64x32 -> 4x2 frags (32 AGPR). Staging:
// one global_load_lds per wave per operand (16 rows each). XOR chunk swizzle.

__device__ __forceinline__ void gemm_body(const _Float16* __restrict__ A,
                                          const _Float16* __restrict__ Bt,
                                          _Float16* __restrict__ C,
                                          int M, int N, int K, int ntiles, int blk,
                                          _Float16* As, _Float16* Bs) {
    int tid = threadIdx.x;
    int lane = tid & 63;
    int wave = tid >> 6;                  // 0..7
    int wm = wave >> 2, wn = wave & 3;    // 2 x 4 wave grid
    int l15 = lane & 15, q = lane >> 4;

    int ntile = blk % ntiles;
    int mtile = blk / ntiles;
    int tileM = mtile * 128;
    int tileN = ntile * 128;

    // staging: wave w stages rows [w*16, w*16+16) of A and of B (1 KB each)
    int srow = lane >> 2;                          // 0..15
    int schunk = (lane & 3) ^ ((lane >> 3) & 3);   // swizzled 16B chunk
    const _Float16* gA = A + (long)(tileM + wave * 16 + srow) * K + schunk * 8;
    const _Float16* gB = Bt + (long)(tileN + wave * 16 + srow) * K + schunk * 8;
    _Float16* lA = As + wave * 512;
    _Float16* lB = Bs + wave * 512;

    int aswz = (q ^ ((l15 >> 1) & 3)) * 8;         // reader chunk (halves)

    f32x4 acc[4][2];
    #pragma unroll
    for (int i = 0; i < 4; ++i)
        #pragma unroll
        for (int j = 0; j < 2; ++j)
            acc[i][j] = (f32x4)(0.f);

    for (int k0 = 0; k0 < K; k0 += 32) {
#ifdef HAS_GLL
        gll16(gA + k0, lA);
        gll16(gB + k0, lB);
#else
        half8 va = *(const half8*)(gA + k0);
        half8 vb = *(const half8*)(gB + k0);
        *(half8*)(lA + lane * 8) = va;
        *(half8*)(lB + lane * 8) = vb;
#endif
        __syncthreads();

        half8 af[4], bf[2];
        #pragma unroll
        for (int i = 0; i < 4; ++i)
            af[i] = *(const half8*)(As + (wm * 64 + i * 16 + l15) * 32 + aswz);
        #pragma unroll
        for (int j = 0; j < 2; ++j)
            bf[j] = *(const half8*)(Bs + (wn * 32 + j * 16 + l15) * 32 + aswz);
        #pragma unroll
        for (int i = 0; i < 4; ++i)
            #pragma unroll
            for (int j = 0; j < 2; ++j)
                acc[i][j] = __builtin_amdgcn_mfma_f32_16x16x32_f16(af[i], bf[j], acc[i][j], 0, 0, 0);
        __syncthreads();
    }

    #pragma unroll
    for (int i = 0; i < 4; ++i) {
        #pragma unroll
        for (int r = 0; r < 4; ++r) {
            int grow = tileM + wm * 64 + i * 16 + q * 4 + r;
            if (grow < M) {
                #pragma unroll
                for (int j = 0; j < 2; ++j) {
                    int gcol = tileN + wn * 32 + j * 16 + l15;
                    C[(long)grow * N + gcol] = (_Float16)acc[i][j][r];
                }
            }
        }
    }
}

// GEMM1 + CSR fill fused: first gb blocks do GEMM, rest do fill.
__global__ __launch_bounds__(512) void k_gemm1_fill(const _Float16* __restrict__ A,
                                                    const _Float16* __restrict__ Bt,
                                                    _Float16* __restrict__ C,
                                                    int M, int N, int K, int ntiles, int gb,
                                                    const int* __restrict__ ei, int* __restrict__ cursor,
                                                    int* __restrict__ csr_src, int E, int Etot) {
    __shared__ _Float16 As[128 * 32];
    __shared__ _Float16 Bs[128 * 32];
    int b = blockIdx.x;
    if (b < gb) {
        gemm_body(A, Bt, C, M, N, K, ntiles, b, As, Bs);
    } else {
        int i = (b - gb) * 512 + threadIdx.x;
        if (i < Etot) {
            int src, dst;
            if (i < E) { src = ei[i]; dst = ei[E + i]; }
            else       { src = i - E; dst = i - E; }
            int pos = atomicAdd(&cursor[dst], 1);
            csr_src[pos] = src;
        }
    }
}

__global__ __launch_bounds__(512) void k_gemm_f16(const _Float16* __restrict__ A,
                                                  const _Float16* __restrict__ Bt,
                                                  _Float16* __restrict__ C,
                                                  int M, int N, int K, int ntiles) {
    __shared__ _Float16 As[128 * 32];
    __shared__ _Float16 Bs[128 * 32];
    gemm_body(A, Bt, C, M, N, K, ntiles, blockIdx.x, As, Bs);
}

// --------------------- fused edge attention, layer 1 -----------------------
// One wave per node, 4 heads (head = lane>>4, 8 ch/lane), 1 edge/iter,
// depth-2 prefetch (r12 anchor). Reduce = DPP row16_sum (r16-proven):
// 4 VALU adds replace 4 dependent ds_permute shuffles per edge.

__global__ __launch_bounds__(256) void k_attn1(const _Float16* __restrict__ xlr,
                                               const float* __restrict__ att, const float* __restrict__ b1,
                                               const int* __restrict__ offs, const int* __restrict__ csr_src,
                                               _Float16* __restrict__ hout, int N) {
    int wave = threadIdx.x >> 6;
    int lane = threadIdx.x & 63;
    int node = blockIdx.x * 4 + wave;
    if (node >= N) return;

    int cbase = (lane >> 4) * 128 + (lane & 15) * 8;
    const _Float16* xlr_l = xlr + cbase;           // per-lane base

    half8 xrv8 = *(const half8*)(xlr_l + ((unsigned)node << 10) + 512);
    float4 atv0 = *(const float4*)(att + cbase);
    float4 atv1 = *(const float4*)(att + cbase + 4);
    h2 xr[4], at[4];
    #pragma unroll
    for (int j = 0; j < 4; ++j) {
        xr[j][0] = xrv8[2 * j]; xr[j][1] = xrv8[2 * j + 1];
    }
    at[0][0] = (_Float16)(atv0.x * LOG2E); at[0][1] = (_Float16)(atv0.y * LOG2E);
    at[1][0] = (_Float16)(atv0.z * LOG2E); at[1][1] = (_Float16)(atv0.w * LOG2E);
    at[2][0] = (_Float16)(atv1.x * LOG2E); at[2][1] = (_Float16)(atv1.y * LOG2E);
    at[3][0] = (_Float16)(atv1.z * LOG2E); at[3][1] = (_Float16)(atv1.w * LOG2E);
    const h2 ns2 = {(_Float16)NEG_SLOPE, (_Float16)NEG_SLOPE};

    float l = 0.f;
    f32x2 acc[4];
    #pragma unroll
    for (int j = 0; j < 4; ++j) acc[j] = (f32x2)(0.f);

    int e0 = offs[node], e1 = offs[node + 1];   // e1 > e0 (self-loop)
    int s_next = csr_src[e0];
    int s_next2 = (e0 + 1 < e1) ? csr_src[e0 + 1] : 0;
    half8 xlv = *(const half8*)(xlr_l + ((unsigned)s_next << 10));

    for (int e = e0; e < e1; ++e) {
        half8 cur = xlv;
        int s_pf = s_next2;
        if (e + 2 < e1) s_next2 = csr_src[e + 2];
        if (e + 1 < e1) xlv = *(const half8*)(xlr_l + ((unsigned)s_pf << 10));

        const h2* cp = (const h2*)&cur;
        float p = 0.f;
        #pragma unroll
        for (int j = 0; j < 4; ++j) {
            h2 t = cp[j] + xr[j];
#if __has_builtin(__builtin_elementwise_max)
            t = __builtin_elementwise_max(t, t * ns2);
#else
            h2 tn = t * ns2;
            t[0] = (t[0] > tn[0]) ? t[0] : tn[0];
            t[1] = (t[1] > tn[1]) ? t[1] : tn[1];
#endif
            p = dot2acc(t, at[j], p);
        }
        p = row16_sum(p);              // DPP reduce-broadcast (r16-proven)
        float w = fast_exp2(p);        // == exp(logit): att pre-scaled by log2e
        l += w;
        f32x2 w2 = {w, w};
        #pragma unroll
        for (int j = 0; j < 4; ++j) {
            f32x2 xf = {(float)cur[2 * j], (float)cur[2 * j + 1]};
            acc[j] = w2 * xf + acc[j];
        }
    }

    float inv = 1.f / (l + 1e-16f);
    float4 b1v0 = *(const float4*)(b1 + cbase);
    float4 b1v1 = *(const float4*)(b1 + cbase + 4);
    float bb[8] = {b1v0.x, b1v0.y, b1v0.z, b1v0.w, b1v1.x, b1v1.y, b1v1.z, b1v1.w};
    half8 ov;
    #pragma unroll
    for (int j = 0; j < 8; ++j) {
        float o = fmaf(acc[j >> 1][j & 1], inv, bb[j]);
        o = (o > 0.f) ? o : (__expf(o) - 1.f);
        ov[j] = (_Float16)o;
    }
    *(half8*)(hout + (long)node * 512 + cbase) = ov;
}

// --------------------- fused edge attention, layer 2 -----------------------
// One wave per node, two edges/iter (half-wave each), 2 ch/lane (D=64).
// Reduce = DPP row16_sum + shfl_xor(16) (exact r16-proven combination).

__global__ __launch_bounds__(256) void k_attn2(const _Float16* __restrict__ xlr2,
                                               const float* __restrict__ att, const float* __restrict__ b2,
                                               const int* __restrict__ offs, const int* __restrict__ csr_src,
                                               float* __restrict__ out, int N) {
    int wave = threadIdx.x >> 6;
    int lane = threadIdx.x & 63;
    int node = blockIdx.x * 4 + wave;
    if (node >= N) return;

    int eh = lane >> 5;
    int hl = lane & 31;
    int ch = hl * 2;
    const _Float16* xlr_l = xlr2 + ch;

    h2 xrh = *(const h2*)(xlr_l + ((unsigned)node << 7) + 64);
    float2 atf = *(const float2*)(att + ch);
    h2 ath; ath[0] = (_Float16)(atf.x * LOG2E); ath[1] = (_Float16)(atf.y * LOG2E);
    const h2 ns2 = {(_Float16)NEG_SLOPE, (_Float16)NEG_SLOPE};

    float l = 0.f;
    f32x2 acc = (f32x2)(0.f);
    int e0 = offs[node], e1 = offs[node + 1];
    int e = e0 + eh;
    h2 cv;
    if (e < e1) {
        int s = csr_src[e];
        cv = *(const h2*)(xlr_l + ((unsigned)s << 7));
    }
    while (e < e1) {
        h2 u = cv;
        int en = e + 2;
        if (en < e1) {
            int s = csr_src[en];
            cv = *(const h2*)(xlr_l + ((unsigned)s << 7));
        }
        h2 t = u + xrh;
#if __has_builtin(__builtin_elementwise_max)
        t = __builtin_elementwise_max(t, t * ns2);
#else
        h2 tn = t * ns2;
        t[0] = (t[0] > tn[0]) ? t[0] : tn[0];
        t[1] = (t[1] > tn[1]) ? t[1] : tn[1];
#endif
        float p = dot2acc(t, ath, 0.f);
        p = row16_sum(p);              // DPP (r16-proven)
        p += __shfl_xor(p, 16, 64);    // cross the two rows of the half-wave
        float w = fast_exp2(p);
        l += w;
        f32x2 w2 = {w, w};
        f32x2 xf = {(float)u[0], (float)u[1]};
        acc = w2 * xf + acc;
        e = en;
    }
    l += __shfl_xor(l, 32, 64);
    acc[0] += __shfl_xor(acc[0], 32, 64);
    acc[1] += __shfl_xor(acc[1], 32, 64);
    if (eh == 0) {
        float inv = 1.f / (l + 1e-16f);
        float2 o;
        o.x = fmaf(acc[0], inv, b2[ch]);
        o.y = fmaf(acc[1], inv, b2[ch + 1]);
        *(float2*)(out + (long)node * 64 + ch) = o;
    }
}

// ---------------------------------------------------------------------------

extern "C" void kernel_launch(void* const* d_in, const int* in_sizes, int n_in,
                              void* d_out, int out_size, void* d_ws, size_t ws_size,
                              hipStream_t stream) {
    const float* x    = (const float*)d_in[0];
    const int*   ei   = (const int*)d_in[1];
    const float* Wl1  = (const float*)d_in[2];
    const float* Wr1  = (const float*)d_in[3];
    const float* att1 = (const float*)d_in[4];
    const float* b1   = (const float*)d_in[5];
    const float* Wl2  = (const float*)d_in[6];
    const float* Wr2  = (const float*)d_in[7];
    const float* att2 = (const float*)d_in[8];
    const float* b2   = (const float*)d_in[9];
    float* out = (float*)d_out;

    const int F_IN = 256;
    int N = in_sizes[0] / F_IN;   // 50000
    int E = in_sizes[1] / 2;      // 400000
    int Etot = E + N;
    int nScanBlocks = (N + 1023) / 1024;
    int mtiles = (N + 127) / 128;
    int Mpad = mtiles * 128;      // A buffers padded so GEMM can load OOB rows

    char* p = (char*)d_ws;
    auto carve = [&](size_t bytes) -> void* {
        void* r = (void*)p;
        p += (bytes + 255) & ~(size_t)255;
        return r;
    };
    _Float16* xh   = (_Float16*)carve((size_t)Mpad * 256 * 2);
    _Float16* W1T  = (_Float16*)carve((size_t)1024 * 256 * 2);
    _Float16* W2T  = (_Float16*)carve((size_t)128 * 512 * 2);
    _Float16* C1   = (_Float16*)carve((size_t)N * 1024 * 2);
    _Float16* h    = (_Float16*)carve((size_t)Mpad * 512 * 2);
    _Float16* C2   = (_Float16*)carve((size_t)N * 128 * 2);
    int* counts  = (int*)carve((size_t)N * 4);
    int* offs    = (int*)carve((size_t)(N + 1) * 4);
    int* cursor  = (int*)carve((size_t)(N + 1) * 4);
    int* partial = (int*)carve((size_t)nScanBlocks * 4);
    int* csr     = (int*)carve((size_t)Etot * 4);

    int gN    = (N + 255) / 256;
    int gEtot = (Etot + 255) / 256;
    int n8    = N * 256 / 8;
    int gCast = (n8 + 255) / 256;

    hipMemsetAsync(counts, 0, (size_t)N * 4, stream);

    // cast_x || count  (independent)
    k_castx_count<<<gEtot + gCast, 256, 0, stream>>>(x, xh, n8, ei, counts, E, Etot, gEtot);

    // cast_w || scan_a  (independent)
    {
        int total = 1024 * 256 + 128 * 512;
        int gW = (total + 1023) / 1024;
        k_castw_scana<<<nScanBlocks + gW, 1024, 0, stream>>>(counts, offs, partial, N, nScanBlocks,
                                                             Wl1, Wr1, Wl2, Wr2, W1T, W2T);
    }
    // merged scan_b + scan_c
    k_scanbc<<<gN, 256, 0, stream>>>(offs, cursor, partial, N, nScanBlocks);

    // layer 1 GEMM (N-tile inner for A reuse) || CSR fill (independent)
    {
        int gb = mtiles * 8;
        int fillBlocks = (Etot + 511) / 512;
        k_gemm1_fill<<<gb + fillBlocks, 512, 0, stream>>>(xh, W1T, C1, N, 1024, 256, 8, gb,
                                                          ei, cursor, csr, E, Etot);
    }
    k_attn1<<<(N + 3) / 4, 256, 0, stream>>>(C1, att1, b1, offs, csr, h, N);

    // layer 2
    k_gemm_f16<<<mtiles, 512, 0, stream>>>(h, W2T, C2, N, 128, 512, 1);
    k_attn2<<<(N + 3) / 4, 256, 0, stream>>>(C2, att2, b2, offs, csr, out, N);
}